// Round 10
// baseline (231.093 us; speedup 1.0000x reference)
//
#include <hip/hip_runtime.h>
#include <math.h>

#define NB 2
#define NPTS 4096
#define NQ 16384
#define QTOT (NB * NQ)   // 32768 queries, batch folded into row index
#define FCATC 448        // 64+128+256 concatenated feature channels per point

typedef _Float16 h8 __attribute__((ext_vector_type(8)));
typedef float v4f __attribute__((ext_vector_type(4)));

// ---------------- k_feG: fused l1+l2+l3+G per 32-point tile + cast riders ----------------
// Compute blocks (0..255): f1,f2,f3 stay in LDS; G[pt][256] = r1[:,3:451] @ [f1|f2|f3];
// per-channel f3 max -> LDS atomicMax -> GMpart[blk][256] (one block owns its row).
// Weights cast fp32->fp16 inline during B-staging.
// Rider blocks (256..295): cast r2 -> Rw2, r3 -> Rw3 for k_tail.
__global__ __launch_bounds__(256) void k_feG(const float* __restrict__ pts,
        const float* __restrict__ w1, const float* __restrict__ b1,
        const float* __restrict__ w2, const float* __restrict__ b2,
        const float* __restrict__ w3, const float* __restrict__ b3,
        const float* __restrict__ r1,
        const float* __restrict__ r2, const float* __restrict__ r3,
        _Float16* __restrict__ G, float* __restrict__ GMpart,
        _Float16* __restrict__ Rw2, _Float16* __restrict__ Rw3) {
    int blk = blockIdx.x;
    int t = threadIdx.x;
    if (blk >= 256) {
        // rider: cast r2 (32768) then r3 (8192), 4 elems/thread
        int g0 = (blk - 256) * 1024 + t * 4;
        #pragma unroll
        for (int j = 0; j < 4; j++) {
            int g = g0 + j;
            if (g < 32768)      Rw2[g] = (_Float16)r2[g];
            else if (g < 40960) Rw3[g - 32768] = (_Float16)r3[g - 32768];
        }
        return;
    }
    __shared__ __align__(16) unsigned char arena[58880];
    _Float16* sF1  = (_Float16*)arena;             // [32][72]  = 4608
    _Float16* sF2  = (_Float16*)(arena + 4608);    // [32][136] = 8704
    _Float16* sF3  = (_Float16*)(arena + 13312);   // [32][264] = 16896
    _Float16* sBst = (_Float16*)(arena + 30208);   // [256][56] = 28672
    __shared__ unsigned smax[256];
    int w = t >> 6, lane = t & 63;
    int m = lane & 15, quad = lane >> 4;
    int P0 = blk * 32;
    int bb = P0 >> 12;
    int p0in = P0 & (NPTS - 1);

    smax[t] = 0u;   // visible to l3's atomicMax via the l2/l3 loop barriers

    // ---- l1: f1[32][64] = relu(W1 @ pts + b1) -> sF1 ----
    {
        int pt = t >> 3;            // 32 pts, 8 threads each
        int cs = (t & 7) * 8;
        const float* pb = pts + (size_t)bb * 3 * NPTS + p0in;
        float px = pb[pt], py = pb[NPTS + pt], pz = pb[2 * NPTS + pt];
        #pragma unroll
        for (int c = cs; c < cs + 8; c++) {
            float v = fmaf(w1[c*3+0], px,
                      fmaf(w1[c*3+1], py,
                      fmaf(w1[c*3+2], pz, b1[c])));
            sF1[pt * 72 + c] = (_Float16)fmaxf(v, 0.f);
        }
    }

    // ---- l2: f2[32][128] = relu(w2 @ f1 + b2) -> sF2 ----
    {
        v4f acc[2][2];
        #pragma unroll
        for (int i = 0; i < 2; i++)
            #pragma unroll
            for (int j = 0; j < 2; j++)
                acc[i][j] = (v4f){0.f, 0.f, 0.f, 0.f};
        for (int kc = 0; kc < 64; kc += 32) {
            __syncthreads();   // first: covers sF1 writes; later: sBst reuse
            #pragma unroll
            for (int i = 0; i < 2; i++) {      // 128 rows x 4 segs = 512 units
                int u = t + i * 256;
                int r = u >> 2, p = u & 3;
                const float* src = w2 + (size_t)r * 64 + kc + p * 8;
                h8 hv;
                #pragma unroll
                for (int j = 0; j < 8; j++) hv[j] = (_Float16)src[j];
                *(h8*)&sBst[r * 56 + p * 8] = hv;
            }
            __syncthreads();
            h8 af[2], bf[2];
            #pragma unroll
            for (int mt = 0; mt < 2; mt++)
                af[mt] = *(const h8*)&sF1[(mt * 16 + m) * 72 + kc + quad * 8];
            #pragma unroll
            for (int nt = 0; nt < 2; nt++)
                bf[nt] = *(const h8*)&sBst[(w * 32 + nt * 16 + m) * 56 + quad * 8];
            #pragma unroll
            for (int mt = 0; mt < 2; mt++)
                #pragma unroll
                for (int nt = 0; nt < 2; nt++)
                    acc[mt][nt] = __builtin_amdgcn_mfma_f32_16x16x32_f16(
                            af[mt], bf[nt], acc[mt][nt], 0, 0, 0);
        }
        #pragma unroll
        for (int nt = 0; nt < 2; nt++) {
            int ch = w * 32 + nt * 16 + m;
            float bb2 = b2[ch];
            #pragma unroll
            for (int mt = 0; mt < 2; mt++)
                #pragma unroll
                for (int r = 0; r < 4; r++) {
                    int pt = mt * 16 + quad * 4 + r;
                    sF2[pt * 136 + ch] = (_Float16)fmaxf(acc[mt][nt][r] + bb2, 0.f);
                }
        }
    }

    // ---- l3: f3[32][256] = relu(w3 @ f2 + b3) -> sF3, channel max -> smax (LDS atomic) ----
    {
        v4f acc[2][4];
        #pragma unroll
        for (int i = 0; i < 2; i++)
            #pragma unroll
            for (int j = 0; j < 4; j++)
                acc[i][j] = (v4f){0.f, 0.f, 0.f, 0.f};
        for (int kc = 0; kc < 128; kc += 32) {
            __syncthreads();   // first: covers sF2 writes; later: sBst reuse
            #pragma unroll
            for (int i = 0; i < 4; i++) {      // 256 rows x 4 segs = 1024 units
                int u = t + i * 256;
                int r = u >> 2, p = u & 3;
                const float* src = w3 + (size_t)r * 128 + kc + p * 8;
                h8 hv;
                #pragma unroll
                for (int j = 0; j < 8; j++) hv[j] = (_Float16)src[j];
                *(h8*)&sBst[r * 56 + p * 8] = hv;
            }
            __syncthreads();
            h8 af[2], bf[4];
            #pragma unroll
            for (int mt = 0; mt < 2; mt++)
                af[mt] = *(const h8*)&sF2[(mt * 16 + m) * 136 + kc + quad * 8];
            #pragma unroll
            for (int nt = 0; nt < 4; nt++)
                bf[nt] = *(const h8*)&sBst[(w * 64 + nt * 16 + m) * 56 + quad * 8];
            #pragma unroll
            for (int mt = 0; mt < 2; mt++)
                #pragma unroll
                for (int nt = 0; nt < 4; nt++)
                    acc[mt][nt] = __builtin_amdgcn_mfma_f32_16x16x32_f16(
                            af[mt], bf[nt], acc[mt][nt], 0, 0, 0);
        }
        #pragma unroll
        for (int nt = 0; nt < 4; nt++) {
            int ch = w * 64 + nt * 16 + m;
            float bb3 = b3[ch];
            float vmax = 0.f;
            #pragma unroll
            for (int mt = 0; mt < 2; mt++)
                #pragma unroll
                for (int r = 0; r < 4; r++) {
                    int pt = mt * 16 + quad * 4 + r;
                    float v = fmaxf(acc[mt][nt][r] + bb3, 0.f);
                    vmax = fmaxf(vmax, v);
                    sF3[pt * 264 + ch] = (_Float16)v;
                }
            // 4 quads hold disjoint point subsets for the same ch -> must reduce
            atomicMax(&smax[ch], __float_as_uint(vmax));
        }
    }
    __syncthreads();   // smax finalized (and sF3 writes done)
    GMpart[(size_t)blk * 256 + t] = __uint_as_float(smax[t]);  // one block owns row

    // ---- G: G[32][256] = r1[:,3:451] @ [f1|f2|f3], K=448, r1 cast inline ----
    {
        v4f acc[2][4];
        #pragma unroll
        for (int i = 0; i < 2; i++)
            #pragma unroll
            for (int j = 0; j < 4; j++)
                acc[i][j] = (v4f){0.f, 0.f, 0.f, 0.f};
        for (int kc = 0; kc < FCATC; kc += 32) {
            __syncthreads();   // sBst reuse
            #pragma unroll
            for (int i = 0; i < 4; i++) {      // 256 rows x 4 segs
                int u = t + i * 256;
                int r = u >> 2, p = u & 3;
                const float* src = r1 + (size_t)r * 707 + 3 + kc + p * 8;  // unaligned: scalar
                h8 hv;
                #pragma unroll
                for (int j = 0; j < 8; j++) hv[j] = (_Float16)src[j];
                *(h8*)&sBst[r * 56 + p * 8] = hv;
            }
            __syncthreads();
            const _Float16* arow; int stride, off;
            if (kc < 64)       { arow = sF1; stride = 72;  off = kc; }
            else if (kc < 192) { arow = sF2; stride = 136; off = kc - 64; }
            else               { arow = sF3; stride = 264; off = kc - 192; }
            h8 af[2], bf[4];
            #pragma unroll
            for (int mt = 0; mt < 2; mt++)
                af[mt] = *(const h8*)&arow[(mt * 16 + m) * stride + off + quad * 8];
            #pragma unroll
            for (int nt = 0; nt < 4; nt++)
                bf[nt] = *(const h8*)&sBst[(w * 64 + nt * 16 + m) * 56 + quad * 8];
            #pragma unroll
            for (int mt = 0; mt < 2; mt++)
                #pragma unroll
                for (int nt = 0; nt < 4; nt++)
                    acc[mt][nt] = __builtin_amdgcn_mfma_f32_16x16x32_f16(
                            af[mt], bf[nt], acc[mt][nt], 0, 0, 0);
        }
        #pragma unroll
        for (int nt = 0; nt < 4; nt++) {
            int ch = w * 64 + nt * 16 + m;
            #pragma unroll
            for (int mt = 0; mt < 2; mt++)
                #pragma unroll
                for (int r = 0; r < 4; r++) {
                    int pt = mt * 16 + quad * 4 + r;
                    G[(size_t)(P0 + pt) * 256 + ch] = (_Float16)acc[mt][nt][r];
                }
        }
    }
}

// ---------------- KNN: round-4 structure verbatim (best measured: ~68 us) ----------------
__global__ __launch_bounds__(512) void k_knn(const float* __restrict__ opts,
        const float* __restrict__ qpts, int* __restrict__ knn_idx,
        float* __restrict__ knn_w) {
    __shared__ float4 sp[NPTS];       // 64 KB
    __shared__ float spd[3][8][64];
    __shared__ int   spi[3][8][64];
    int t = threadIdx.x;
    int b = blockIdx.x >> 8;
    int q0 = (blockIdx.x & 255) << 6;
    const float* ob = opts + b * 3 * NPTS;
    for (int i = t; i < NPTS; i += 512) {
        float x = ob[i], y = ob[NPTS + i], z = ob[2 * NPTS + i];
        float o2 = __fadd_rn(__fadd_rn(__fmul_rn(x, x), __fmul_rn(y, y)), __fmul_rn(z, z));
        sp[i] = make_float4(x, y, z, o2);
    }
    __syncthreads();
    int lane = t & 63;
    int w = t >> 6;
    int q = q0 + lane;
    float qx = qpts[b * 3 * NQ + q];
    float qy = qpts[b * 3 * NQ + NQ + q];
    float qz = qpts[b * 3 * NQ + 2 * NQ + q];
    float q2 = __fadd_rn(__fadd_rn(__fmul_rn(qx, qx), __fmul_rn(qy, qy)), __fmul_rn(qz, qz));

    int base = w << 9;
    float d0 = 1e30f, d1 = 1e30f, d2v = 1e30f;
    int i0 = 0, i1 = 0, i2 = 0;
    float e0 = 1e30f, e1 = 1e30f, e2v = 1e30f;
    int j0 = 0, j1 = 0, j2 = 0;
    #pragma unroll 2
    for (int k = 0; k < 256; k++) {
        int na = base + k, nb2 = base + 256 + k;
        float4 pa = sp[na];
        float4 pb = sp[nb2];
        float cra = __fadd_rn(__fadd_rn(__fmul_rn(qx, pa.x), __fmul_rn(qy, pa.y)), __fmul_rn(qz, pa.z));
        float da = __fsub_rn(__fadd_rn(q2, pa.w), __fmul_rn(2.f, cra));
        float crb = __fadd_rn(__fadd_rn(__fmul_rn(qx, pb.x), __fmul_rn(qy, pb.y)), __fmul_rn(qz, pb.z));
        float db = __fsub_rn(__fadd_rn(q2, pb.w), __fmul_rn(2.f, crb));
        if (da < d2v) {                 // strict <: ascending idx keeps earlier on ties
            if (da < d1) {
                d2v = d1; i2 = i1;
                if (da < d0) { d1 = d0; i1 = i0; d0 = da; i0 = na; }
                else         { d1 = da; i1 = na; }
            } else { d2v = da; i2 = na; }
        }
        if (db < e2v) {
            if (db < e1) {
                e2v = e1; j2 = j1;
                if (db < e0) { e1 = e0; j1 = j0; e0 = db; j0 = nb2; }
                else         { e1 = db; j1 = nb2; }
            } else { e2v = db; j2 = nb2; }
        }
    }
    // merge chain B into A (lexicographic (d, idx) preserves top_k stability)
    {
        float md[3] = {e0, e1, e2v};
        int   mi[3] = {j0, j1, j2};
        #pragma unroll
        for (int m = 0; m < 3; m++) {
            float d = md[m]; int i = mi[m];
            if (d < d2v || (d == d2v && i < i2)) {
                if (d < d1 || (d == d1 && i < i1)) {
                    d2v = d1; i2 = i1;
                    if (d < d0 || (d == d0 && i < i0)) { d1 = d0; i1 = i0; d0 = d; i0 = i; }
                    else { d1 = d; i1 = i; }
                } else { d2v = d; i2 = i; }
            }
        }
    }
    spd[0][w][lane] = d0;  spi[0][w][lane] = i0;
    spd[1][w][lane] = d1;  spi[1][w][lane] = i1;
    spd[2][w][lane] = d2v; spi[2][w][lane] = i2;
    __syncthreads();
    if (t < 64) {
        d0 = spd[0][0][t]; i0 = spi[0][0][t];
        d1 = spd[1][0][t]; i1 = spi[1][0][t];
        d2v = spd[2][0][t]; i2 = spi[2][0][t];
        for (int p = 1; p < 8; p++) {
            #pragma unroll
            for (int m = 0; m < 3; m++) {
                float d = spd[m][p][t]; int i = spi[m][p][t];
                if (d < d2v || (d == d2v && i < i2)) {
                    if (d < d1 || (d == d1 && i < i1)) {
                        d2v = d1; i2 = i1;
                        if (d < d0 || (d == d0 && i < i0)) { d1 = d0; i1 = i0; d0 = d; i0 = i; }
                        else { d1 = d; i1 = i; }
                    } else { d2v = d; i2 = i; }
                }
            }
        }
        int ids[3] = {i0, i1, i2};
        float r[3];
        float s = 0.f;
        #pragma unroll
        for (int m = 0; m < 3; m++) {
            float4 p = sp[ids[m]];
            float dx = __fsub_rn(p.x, qx), dy = __fsub_rn(p.y, qy), dz = __fsub_rn(p.z, qz);
            float dd = __fadd_rn(__fadd_rn(__fmul_rn(dx, dx), __fmul_rn(dy, dy)), __fmul_rn(dz, dz));
            float dist = sqrtf(dd);
            r[m] = 1.f / (__fadd_rn(dist, 1e-8f));
            s += r[m];
        }
        int basei = (b * NQ + q) * 3;
        #pragma unroll
        for (int m = 0; m < 3; m++) {
            knn_idx[basei + m] = ids[m];
            knn_w[basei + m]   = r[m] / s;
        }
    }
}

// ---------------- k_tail: gmax/CB phase-0 + interp + r2 + r3 + r4, 64 q/block ----------------
__global__ __launch_bounds__(256) void k_tail(
        const float* __restrict__ qpts, const _Float16* __restrict__ G,
        const float* __restrict__ GMpart, const int* __restrict__ knn_idx,
        const float* __restrict__ knn_w, const float* __restrict__ r1,
        const float* __restrict__ rb1,
        const _Float16* __restrict__ Rw2, const float* __restrict__ rb2,
        const _Float16* __restrict__ Rw3, const float* __restrict__ rb3,
        const float* __restrict__ r4, const float* __restrict__ rb4,
        float* __restrict__ out) {
    __shared__ __align__(16) unsigned char arena[48128];
    _Float16* sH1  = (_Float16*)arena;             // [64][264] = 33792 B
    _Float16* sBst = (_Float16*)(arena + 33792);   // r2 B-stage [128][56] = 14336 B
    _Float16* sH2  = (_Float16*)arena;             // [64][136] = 17408 (aliases sH1)
    _Float16* sH3  = (_Float16*)(arena + 17408);   // [64][72]  = 9216
    _Float16* sW3  = (_Float16*)(arena + 33792);   // r3 W-stage [64][56] = 7168
    float*    s_gm = (float*)arena;                // [256] temp during phase-0
    __shared__ int   s_id[192];
    __shared__ float s_wt[192];
    __shared__ float s_qp[3][64];
    __shared__ float s_wq[3][256];
    __shared__ float s_cb[256];
    __shared__ float sw4[64];
    int t = threadIdx.x;
    int w = t >> 6, lane = t & 63;
    int m = lane & 15, quad = lane >> 4;
    int q0 = blockIdx.x * 64;
    int b = q0 >> 14;
    int qin = q0 & (NQ - 1);

    if (t < 192) {
        s_id[t] = knn_idx[q0 * 3 + t];
        s_wt[t] = knn_w[q0 * 3 + t];
        int d = t >> 6, j = t & 63;
        s_qp[d][j] = qpts[(size_t)b * 3 * NQ + d * NQ + qin + j];
    }
    s_wq[0][t] = r1[(size_t)t * 707 + 0];
    s_wq[1][t] = r1[(size_t)t * 707 + 1];
    s_wq[2][t] = r1[(size_t)t * 707 + 2];
    if (t < 64) sw4[t] = r4[t];
    // phase-0a: reduce GMpart rows of this batch (coalesced); max is order-exact
    {
        float mx = 0.f;
        const float* gp = GMpart + (size_t)b * 128 * 256 + t;
        #pragma unroll 8
        for (int r = 0; r < 128; r++) mx = fmaxf(mx, gp[(size_t)r * 256]);
        s_gm[t] = mx;
    }
    __syncthreads();
    // phase-0b: cb[t] = rb1[t] + r1[t,451:707] . gmax  (same fmaf order as before)
    {
        const float* wrow = r1 + (size_t)t * 707 + 451;
        float acc = rb1[t];
        #pragma unroll 8
        for (int c = 0; c < 256; c++) acc = fmaf(wrow[c], s_gm[c], acc);
        s_cb[t] = acc;
    }
    __syncthreads();   // s_cb visible; arena (s_gm) free for sH1

    // ---- interp: build h1 tile [64 q][256 ch] in LDS ----
    {
        int cg = (t & 31) * 8;
        int js = t >> 5;
        float wq0[8], wq1[8], wq2[8], cbv[8];
        #pragma unroll
        for (int u = 0; u < 8; u++) {
            wq0[u] = s_wq[0][cg + u];
            wq1[u] = s_wq[1][cg + u];
            wq2[u] = s_wq[2][cg + u];
            cbv[u] = s_cb[cg + u];
        }
        const _Float16* Gb = G + (size_t)b * NPTS * 256;
        #pragma unroll
        for (int jj = 0; jj < 8; jj++) {
            int j = js + jj * 8;
            int i0 = s_id[j * 3 + 0], i1 = s_id[j * 3 + 1], i2 = s_id[j * 3 + 2];
            float w0 = s_wt[j * 3 + 0], w1 = s_wt[j * 3 + 1], w2 = s_wt[j * 3 + 2];
            float qx = s_qp[0][j], qy = s_qp[1][j], qz = s_qp[2][j];
            h8 g0 = *(const h8*)&Gb[(size_t)i0 * 256 + cg];
            h8 g1 = *(const h8*)&Gb[(size_t)i1 * 256 + cg];
            h8 g2 = *(const h8*)&Gb[(size_t)i2 * 256 + cg];
            h8 hv;
            #pragma unroll
            for (int u = 0; u < 8; u++) {
                float acc = cbv[u];
                acc = fmaf(wq0[u], qx, acc);
                acc = fmaf(wq1[u], qy, acc);
                acc = fmaf(wq2[u], qz, acc);
                acc = fmaf(w0, (float)g0[u], acc);
                acc = fmaf(w1, (float)g1[u], acc);
                acc = fmaf(w2, (float)g2[u], acc);
                hv[u] = (_Float16)fmaxf(acc, 0.f);
            }
            *(h8*)&sH1[j * 264 + cg] = hv;
        }
    }

    // ---- r2: h2(64q x 128ch) = relu(Rw2 @ h1); A-frags straight from sH1 ----
    float h2v[4][2][4];
    {
        v4f acc[4][2];
        #pragma unroll
        for (int i = 0; i < 4; i++)
            #pragma unroll
            for (int j = 0; j < 2; j++)
                acc[i][j] = (v4f){0.f, 0.f, 0.f, 0.f};
        for (int kc = 0; kc < 256; kc += 32) {
            __syncthreads();   // first: sH1 writes; later: sBst reuse
            #pragma unroll
            for (int i = 0; i < 2; i++) {
                int e = t + i * 256;
                int r = e >> 2, p = e & 3;
                *(float4*)&sBst[r * 56 + p * 8] =
                    *(const float4*)&Rw2[(size_t)r * 256 + kc + p * 8];
            }
            __syncthreads();
            h8 af[4], bf[2];
            #pragma unroll
            for (int mt = 0; mt < 4; mt++)
                af[mt] = *(const h8*)&sH1[(mt * 16 + m) * 264 + kc + quad * 8];
            #pragma unroll
            for (int nt = 0; nt < 2; nt++)
                bf[nt] = *(const h8*)&sBst[(w * 32 + nt * 16 + m) * 56 + quad * 8];
            #pragma unroll
            for (int mt = 0; mt < 4; mt++)
                #pragma unroll
                for (int nt = 0; nt < 2; nt++)
                    acc[mt][nt] = __builtin_amdgcn_mfma_f32_16x16x32_f16(
                            af[mt], bf[nt], acc[mt][nt], 0, 0, 0);
        }
        #pragma unroll
        for (int nt = 0; nt < 2; nt++) {
            int ch = w * 32 + nt * 16 + m;
            float bb2 = rb2[ch];
            #pragma unroll
            for (int mt = 0; mt < 4; mt++)
                #pragma unroll
                for (int r = 0; r < 4; r++)
                    h2v[mt][nt][r] = fmaxf(acc[mt][nt][r] + bb2, 0.f);
        }
    }
    __syncthreads();   // all sH1 reads done -> safe to overwrite with sH2
    {
        #pragma unroll
        for (int nt = 0; nt < 2; nt++) {
            int ch = w * 32 + nt * 16 + m;
            #pragma unroll
            for (int mt = 0; mt < 4; mt++)
                #pragma unroll
                for (int r = 0; r < 4; r++) {
                    int ql = mt * 16 + quad * 4 + r;
                    sH2[ql * 136 + ch] = (_Float16)h2v[mt][nt][r];
                }
        }
    }

    // ---- r3: h3(64q x 64ch) = relu(Rw3 @ h2) ----
    float h3v[4][4];
    {
        v4f acc[4];
        #pragma unroll
        for (int i = 0; i < 4; i++) acc[i] = (v4f){0.f, 0.f, 0.f, 0.f};
        for (int kc = 0; kc < 128; kc += 32) {
            __syncthreads();   // first: sH2 writes; later: sW3 reuse
            {
                int r = t >> 2, p = t & 3;   // 64 rows x 4 segs = 256 units
                *(float4*)&sW3[r * 56 + p * 8] =
                    *(const float4*)&Rw3[(size_t)r * 128 + kc + p * 8];
            }
            __syncthreads();
            h8 af[4], bf;
            #pragma unroll
            for (int mt = 0; mt < 4; mt++)
                af[mt] = *(const h8*)&sH2[(mt * 16 + m) * 136 + kc + quad * 8];
            bf = *(const h8*)&sW3[(w * 16 + m) * 56 + quad * 8];
            #pragma unroll
            for (int mt = 0; mt < 4; mt++)
                acc[mt] = __builtin_amdgcn_mfma_f32_16x16x32_f16(
                        af[mt], bf, acc[mt], 0, 0, 0);
        }
        int ch = w * 16 + m;
        float bb3 = rb3[ch];
        #pragma unroll
        for (int mt = 0; mt < 4; mt++)
            #pragma unroll
            for (int r = 0; r < 4; r++)
                h3v[mt][r] = fmaxf(acc[mt][r] + bb3, 0.f);
    }
    __syncthreads();
    {
        int ch = w * 16 + m;
        #pragma unroll
        for (int mt = 0; mt < 4; mt++)
            #pragma unroll
            for (int r = 0; r < 4; r++) {
                int ql = mt * 16 + quad * 4 + r;
                sH3[ch * 72 + ql] = (_Float16)h3v[mt][r];
            }
    }
    __syncthreads();

    // ---- r4: out = r4 . h3 + rb4 ----
    if (t < 64) {
        float acc = rb4[0];
        #pragma unroll 16
        for (int c = 0; c < 64; c++)
            acc = fmaf((float)sH3[c * 72 + t], sw4[c], acc);
        out[q0 + t] = acc;
    }
}

extern "C" void kernel_launch(void* const* d_in, const int* in_sizes, int n_in,
                              void* d_out, int out_size, void* d_ws, size_t ws_size,
                              hipStream_t stream) {
    const float* opts = (const float*)d_in[0];
    const float* qpts = (const float*)d_in[1];
    const float* w1  = (const float*)d_in[2];
    const float* b1  = (const float*)d_in[3];
    const float* w2  = (const float*)d_in[4];
    const float* b2  = (const float*)d_in[5];
    const float* w3  = (const float*)d_in[6];
    const float* b3  = (const float*)d_in[7];
    const float* r1  = (const float*)d_in[8];
    const float* rb1 = (const float*)d_in[9];
    const float* r2  = (const float*)d_in[10];
    const float* rb2 = (const float*)d_in[11];
    const float* r3  = (const float*)d_in[12];
    const float* rb3 = (const float*)d_in[13];
    const float* r4  = (const float*)d_in[14];
    const float* rb4 = (const float*)d_in[15];
    float* out = (float*)d_out;

    unsigned char* p = (unsigned char*)d_ws;
    float* GMpart = (float*)p;      p += (size_t)256 * 256 * 4;       // [blk][ch]
    int*   IDX = (int*)p;           p += (size_t)NB * NQ * 3 * 4;
    float* WT = (float*)p;          p += (size_t)NB * NQ * 3 * 4;
    _Float16* Rw2 = (_Float16*)p;   p += (size_t)128 * 256 * 2;
    _Float16* Rw3 = (_Float16*)p;   p += (size_t)64 * 128 * 2;
    _Float16* G = (_Float16*)p;     p += (size_t)NB * NPTS * 256 * 2;

    k_feG<<<296, 256, 0, stream>>>(opts, w1, b1, w2, b2, w3, b3, r1, r2, r3,
                                   G, GMpart, Rw2, Rw3);
    k_knn<<<512, 512, 0, stream>>>(opts, qpts, IDX, WT);
    k_tail<<<QTOT / 64, 256, 0, stream>>>(qpts, G, GMpart, IDX, WT, r1, rb1,
                                          Rw2, rb2, Rw3, rb3, r4, rb4, out);
}

// Round 11
// 219.977 us; speedup vs baseline: 1.0505x; 1.0505x over previous
//
#include <hip/hip_runtime.h>
#include <math.h>

#define NB 2
#define NPTS 4096
#define NQ 16384
#define QTOT (NB * NQ)   // 32768 queries, batch folded into row index
#define FCATC 448        // 64+128+256 concatenated feature channels per point

typedef _Float16 h8 __attribute__((ext_vector_type(8)));
typedef float v4f __attribute__((ext_vector_type(4)));

// ---------------- k_pre: all weight casts, once, vectorized ----------------
// 768 blocks x 256 threads = 196608 = 114688(Rw1) + 32768(Rw2) + 8192(Rw3)
//                                   + 8192(Ew2) + 32768(Ew3)
__global__ __launch_bounds__(256) void k_pre(
        const float* __restrict__ r1, const float* __restrict__ r2,
        const float* __restrict__ r3, const float* __restrict__ w2,
        const float* __restrict__ w3,
        _Float16* __restrict__ Rw1, _Float16* __restrict__ Rw2,
        _Float16* __restrict__ Rw3, _Float16* __restrict__ Ew2,
        _Float16* __restrict__ Ew3) {
    int g = blockIdx.x * 256 + threadIdx.x;
    if (g < 114688) {                       // Rw1 = r1[:,3:451] packed [256][448]
        int o = g / FCATC, k = g - o * FCATC;
        Rw1[g] = (_Float16)r1[(size_t)o * 707 + 3 + k];
    } else if (g < 147456) {                // Rw2 = r2 (128x256)
        int i = g - 114688;
        Rw2[i] = (_Float16)r2[i];
    } else if (g < 155648) {                // Rw3 = r3 (64x128)
        int i = g - 147456;
        Rw3[i] = (_Float16)r3[i];
    } else if (g < 163840) {                // Ew2 = w2 (128x64)
        int i = g - 155648;
        Ew2[i] = (_Float16)w2[i];
    } else {                                // Ew3 = w3 (256x128)
        int i = g - 163840;
        Ew3[i] = (_Float16)w3[i];
    }
}

// ---------------- k_feG2: fused l1+l2+l3+G per 32-point tile (fp16 weights) ----------------
// f1,f2,f3 stay in LDS; G[pt][256] = Rw1 @ [f1|f2|f3]; per-channel f3 max
// -> LDS atomicMax -> GMpart[blk][256] (one block owns its row).
__global__ __launch_bounds__(256) void k_feG2(const float* __restrict__ pts,
        const float* __restrict__ w1, const float* __restrict__ b1,
        const _Float16* __restrict__ Ew2, const float* __restrict__ b2,
        const _Float16* __restrict__ Ew3, const float* __restrict__ b3,
        const _Float16* __restrict__ Rw1,
        _Float16* __restrict__ G, float* __restrict__ GMpart) {
    __shared__ __align__(16) unsigned char arena[58880];
    _Float16* sF1  = (_Float16*)arena;             // [32][72]  = 4608
    _Float16* sF2  = (_Float16*)(arena + 4608);    // [32][136] = 8704
    _Float16* sF3  = (_Float16*)(arena + 13312);   // [32][264] = 16896
    _Float16* sBst = (_Float16*)(arena + 30208);   // [256][56] = 28672
    __shared__ unsigned smax[256];
    int blk = blockIdx.x;
    int t = threadIdx.x;
    int w = t >> 6, lane = t & 63;
    int m = lane & 15, quad = lane >> 4;
    int P0 = blk * 32;
    int bb = P0 >> 12;
    int p0in = P0 & (NPTS - 1);

    smax[t] = 0u;   // finalized before use via the l2/l3 loop barriers

    // ---- l1: f1[32][64] = relu(W1 @ pts + b1) -> sF1 ----
    {
        int pt = t >> 3;            // 32 pts, 8 threads each
        int cs = (t & 7) * 8;
        const float* pb = pts + (size_t)bb * 3 * NPTS + p0in;
        float px = pb[pt], py = pb[NPTS + pt], pz = pb[2 * NPTS + pt];
        #pragma unroll
        for (int c = cs; c < cs + 8; c++) {
            float v = fmaf(w1[c*3+0], px,
                      fmaf(w1[c*3+1], py,
                      fmaf(w1[c*3+2], pz, b1[c])));
            sF1[pt * 72 + c] = (_Float16)fmaxf(v, 0.f);
        }
    }

    // ---- l2: f2[32][128] = relu(Ew2 @ f1 + b2) -> sF2 ----
    {
        v4f acc[2][2];
        #pragma unroll
        for (int i = 0; i < 2; i++)
            #pragma unroll
            for (int j = 0; j < 2; j++)
                acc[i][j] = (v4f){0.f, 0.f, 0.f, 0.f};
        for (int kc = 0; kc < 64; kc += 32) {
            __syncthreads();   // first: covers sF1 writes; later: sBst reuse
            #pragma unroll
            for (int i = 0; i < 2; i++) {      // 128 rows x 4 segs = 512 units
                int u = t + i * 256;
                int r = u >> 2, p = u & 3;
                *(float4*)&sBst[r * 56 + p * 8] =
                    *(const float4*)&Ew2[(size_t)r * 64 + kc + p * 8];
            }
            __syncthreads();
            h8 af[2], bf[2];
            #pragma unroll
            for (int mt = 0; mt < 2; mt++)
                af[mt] = *(const h8*)&sF1[(mt * 16 + m) * 72 + kc + quad * 8];
            #pragma unroll
            for (int nt = 0; nt < 2; nt++)
                bf[nt] = *(const h8*)&sBst[(w * 32 + nt * 16 + m) * 56 + quad * 8];
            #pragma unroll
            for (int mt = 0; mt < 2; mt++)
                #pragma unroll
                for (int nt = 0; nt < 2; nt++)
                    acc[mt][nt] = __builtin_amdgcn_mfma_f32_16x16x32_f16(
                            af[mt], bf[nt], acc[mt][nt], 0, 0, 0);
        }
        #pragma unroll
        for (int nt = 0; nt < 2; nt++) {
            int ch = w * 32 + nt * 16 + m;
            float bb2 = b2[ch];
            #pragma unroll
            for (int mt = 0; mt < 2; mt++)
                #pragma unroll
                for (int r = 0; r < 4; r++) {
                    int pt = mt * 16 + quad * 4 + r;
                    sF2[pt * 136 + ch] = (_Float16)fmaxf(acc[mt][nt][r] + bb2, 0.f);
                }
        }
    }

    // ---- l3: f3[32][256] = relu(Ew3 @ f2 + b3) -> sF3, channel max -> smax ----
    {
        v4f acc[2][4];
        #pragma unroll
        for (int i = 0; i < 2; i++)
            #pragma unroll
            for (int j = 0; j < 4; j++)
                acc[i][j] = (v4f){0.f, 0.f, 0.f, 0.f};
        for (int kc = 0; kc < 128; kc += 32) {
            __syncthreads();   // first: covers sF2 writes; later: sBst reuse
            #pragma unroll
            for (int i = 0; i < 4; i++) {      // 256 rows x 4 segs = 1024 units
                int u = t + i * 256;
                int r = u >> 2, p = u & 3;
                *(float4*)&sBst[r * 56 + p * 8] =
                    *(const float4*)&Ew3[(size_t)r * 128 + kc + p * 8];
            }
            __syncthreads();
            h8 af[2], bf[4];
            #pragma unroll
            for (int mt = 0; mt < 2; mt++)
                af[mt] = *(const h8*)&sF2[(mt * 16 + m) * 136 + kc + quad * 8];
            #pragma unroll
            for (int nt = 0; nt < 4; nt++)
                bf[nt] = *(const h8*)&sBst[(w * 64 + nt * 16 + m) * 56 + quad * 8];
            #pragma unroll
            for (int mt = 0; mt < 2; mt++)
                #pragma unroll
                for (int nt = 0; nt < 4; nt++)
                    acc[mt][nt] = __builtin_amdgcn_mfma_f32_16x16x32_f16(
                            af[mt], bf[nt], acc[mt][nt], 0, 0, 0);
        }
        #pragma unroll
        for (int nt = 0; nt < 4; nt++) {
            int ch = w * 64 + nt * 16 + m;
            float bb3 = b3[ch];
            float vmax = 0.f;
            #pragma unroll
            for (int mt = 0; mt < 2; mt++)
                #pragma unroll
                for (int r = 0; r < 4; r++) {
                    int pt = mt * 16 + quad * 4 + r;
                    float v = fmaxf(acc[mt][nt][r] + bb3, 0.f);
                    vmax = fmaxf(vmax, v);
                    sF3[pt * 264 + ch] = (_Float16)v;
                }
            // 4 quads hold disjoint point subsets for the same ch -> must reduce
            atomicMax(&smax[ch], __float_as_uint(vmax));
        }
    }
    __syncthreads();   // smax finalized (and sF3 writes done)
    GMpart[(size_t)blk * 256 + t] = __uint_as_float(smax[t]);  // one block owns row

    // ---- G: G[32][256] = Rw1 @ [f1|f2|f3], K=448 ----
    {
        v4f acc[2][4];
        #pragma unroll
        for (int i = 0; i < 2; i++)
            #pragma unroll
            for (int j = 0; j < 4; j++)
                acc[i][j] = (v4f){0.f, 0.f, 0.f, 0.f};
        for (int kc = 0; kc < FCATC; kc += 32) {
            __syncthreads();   // sBst reuse
            #pragma unroll
            for (int i = 0; i < 4; i++) {      // 256 rows x 4 segs
                int u = t + i * 256;
                int r = u >> 2, p = u & 3;
                *(float4*)&sBst[r * 56 + p * 8] =
                    *(const float4*)&Rw1[(size_t)r * FCATC + kc + p * 8];
            }
            __syncthreads();
            const _Float16* arow; int stride, off;
            if (kc < 64)       { arow = sF1; stride = 72;  off = kc; }
            else if (kc < 192) { arow = sF2; stride = 136; off = kc - 64; }
            else               { arow = sF3; stride = 264; off = kc - 192; }
            h8 af[2], bf[4];
            #pragma unroll
            for (int mt = 0; mt < 2; mt++)
                af[mt] = *(const h8*)&arow[(mt * 16 + m) * stride + off + quad * 8];
            #pragma unroll
            for (int nt = 0; nt < 4; nt++)
                bf[nt] = *(const h8*)&sBst[(w * 64 + nt * 16 + m) * 56 + quad * 8];
            #pragma unroll
            for (int mt = 0; mt < 2; mt++)
                #pragma unroll
                for (int nt = 0; nt < 4; nt++)
                    acc[mt][nt] = __builtin_amdgcn_mfma_f32_16x16x32_f16(
                            af[mt], bf[nt], acc[mt][nt], 0, 0, 0);
        }
        #pragma unroll
        for (int nt = 0; nt < 4; nt++) {
            int ch = w * 64 + nt * 16 + m;
            #pragma unroll
            for (int mt = 0; mt < 2; mt++)
                #pragma unroll
                for (int r = 0; r < 4; r++) {
                    int pt = mt * 16 + quad * 4 + r;
                    G[(size_t)(P0 + pt) * 256 + ch] = (_Float16)acc[mt][nt][r];
                }
        }
    }
}

// ---------------- KNN: round-4 structure verbatim (best measured: ~68 us) ----------------
__global__ __launch_bounds__(512) void k_knn(const float* __restrict__ opts,
        const float* __restrict__ qpts, int* __restrict__ knn_idx,
        float* __restrict__ knn_w) {
    __shared__ float4 sp[NPTS];       // 64 KB
    __shared__ float spd[3][8][64];
    __shared__ int   spi[3][8][64];
    int t = threadIdx.x;
    int b = blockIdx.x >> 8;
    int q0 = (blockIdx.x & 255) << 6;
    const float* ob = opts + b * 3 * NPTS;
    for (int i = t; i < NPTS; i += 512) {
        float x = ob[i], y = ob[NPTS + i], z = ob[2 * NPTS + i];
        float o2 = __fadd_rn(__fadd_rn(__fmul_rn(x, x), __fmul_rn(y, y)), __fmul_rn(z, z));
        sp[i] = make_float4(x, y, z, o2);
    }
    __syncthreads();
    int lane = t & 63;
    int w = t >> 6;
    int q = q0 + lane;
    float qx = qpts[b * 3 * NQ + q];
    float qy = qpts[b * 3 * NQ + NQ + q];
    float qz = qpts[b * 3 * NQ + 2 * NQ + q];
    float q2 = __fadd_rn(__fadd_rn(__fmul_rn(qx, qx), __fmul_rn(qy, qy)), __fmul_rn(qz, qz));

    int base = w << 9;
    float d0 = 1e30f, d1 = 1e30f, d2v = 1e30f;
    int i0 = 0, i1 = 0, i2 = 0;
    float e0 = 1e30f, e1 = 1e30f, e2v = 1e30f;
    int j0 = 0, j1 = 0, j2 = 0;
    #pragma unroll 2
    for (int k = 0; k < 256; k++) {
        int na = base + k, nb2 = base + 256 + k;
        float4 pa = sp[na];
        float4 pb = sp[nb2];
        float cra = __fadd_rn(__fadd_rn(__fmul_rn(qx, pa.x), __fmul_rn(qy, pa.y)), __fmul_rn(qz, pa.z));
        float da = __fsub_rn(__fadd_rn(q2, pa.w), __fmul_rn(2.f, cra));
        float crb = __fadd_rn(__fadd_rn(__fmul_rn(qx, pb.x), __fmul_rn(qy, pb.y)), __fmul_rn(qz, pb.z));
        float db = __fsub_rn(__fadd_rn(q2, pb.w), __fmul_rn(2.f, crb));
        if (da < d2v) {                 // strict <: ascending idx keeps earlier on ties
            if (da < d1) {
                d2v = d1; i2 = i1;
                if (da < d0) { d1 = d0; i1 = i0; d0 = da; i0 = na; }
                else         { d1 = da; i1 = na; }
            } else { d2v = da; i2 = na; }
        }
        if (db < e2v) {
            if (db < e1) {
                e2v = e1; j2 = j1;
                if (db < e0) { e1 = e0; j1 = j0; e0 = db; j0 = nb2; }
                else         { e1 = db; j1 = nb2; }
            } else { e2v = db; j2 = nb2; }
        }
    }
    // merge chain B into A (lexicographic (d, idx) preserves top_k stability)
    {
        float md[3] = {e0, e1, e2v};
        int   mi[3] = {j0, j1, j2};
        #pragma unroll
        for (int m = 0; m < 3; m++) {
            float d = md[m]; int i = mi[m];
            if (d < d2v || (d == d2v && i < i2)) {
                if (d < d1 || (d == d1 && i < i1)) {
                    d2v = d1; i2 = i1;
                    if (d < d0 || (d == d0 && i < i0)) { d1 = d0; i1 = i0; d0 = d; i0 = i; }
                    else { d1 = d; i1 = i; }
                } else { d2v = d; i2 = i; }
            }
        }
    }
    spd[0][w][lane] = d0;  spi[0][w][lane] = i0;
    spd[1][w][lane] = d1;  spi[1][w][lane] = i1;
    spd[2][w][lane] = d2v; spi[2][w][lane] = i2;
    __syncthreads();
    if (t < 64) {
        d0 = spd[0][0][t]; i0 = spi[0][0][t];
        d1 = spd[1][0][t]; i1 = spi[1][0][t];
        d2v = spd[2][0][t]; i2 = spi[2][0][t];
        for (int p = 1; p < 8; p++) {
            #pragma unroll
            for (int m = 0; m < 3; m++) {
                float d = spd[m][p][t]; int i = spi[m][p][t];
                if (d < d2v || (d == d2v && i < i2)) {
                    if (d < d1 || (d == d1 && i < i1)) {
                        d2v = d1; i2 = i1;
                        if (d < d0 || (d == d0 && i < i0)) { d1 = d0; i1 = i0; d0 = d; i0 = i; }
                        else { d1 = d; i1 = i; }
                    } else { d2v = d; i2 = i; }
                }
            }
        }
        int ids[3] = {i0, i1, i2};
        float r[3];
        float s = 0.f;
        #pragma unroll
        for (int m = 0; m < 3; m++) {
            float4 p = sp[ids[m]];
            float dx = __fsub_rn(p.x, qx), dy = __fsub_rn(p.y, qy), dz = __fsub_rn(p.z, qz);
            float dd = __fadd_rn(__fadd_rn(__fmul_rn(dx, dx), __fmul_rn(dy, dy)), __fmul_rn(dz, dz));
            float dist = sqrtf(dd);
            r[m] = 1.f / (__fadd_rn(dist, 1e-8f));
            s += r[m];
        }
        int basei = (b * NQ + q) * 3;
        #pragma unroll
        for (int m = 0; m < 3; m++) {
            knn_idx[basei + m] = ids[m];
            knn_w[basei + m]   = r[m] / s;
        }
    }
}

// ---------------- k_tail: gmax/CB phase-0 + interp + r2 + r3 + r4, 64 q/block ----------------
__global__ __launch_bounds__(256) void k_tail(
        const float* __restrict__ qpts, const _Float16* __restrict__ G,
        const float* __restrict__ GMpart, const int* __restrict__ knn_idx,
        const float* __restrict__ knn_w, const float* __restrict__ r1,
        const float* __restrict__ rb1,
        const _Float16* __restrict__ Rw2, const float* __restrict__ rb2,
        const _Float16* __restrict__ Rw3, const float* __restrict__ rb3,
        const float* __restrict__ r4, const float* __restrict__ rb4,
        float* __restrict__ out) {
    __shared__ __align__(16) unsigned char arena[48128];
    _Float16* sH1  = (_Float16*)arena;             // [64][264] = 33792 B
    _Float16* sBst = (_Float16*)(arena + 33792);   // r2 B-stage [128][56] = 14336 B
    _Float16* sH2  = (_Float16*)arena;             // [64][136] = 17408 (aliases sH1)
    _Float16* sH3  = (_Float16*)(arena + 17408);   // [64][72]  = 9216
    _Float16* sW3  = (_Float16*)(arena + 33792);   // r3 W-stage [64][56] = 7168
    float*    s_gm = (float*)arena;                // [256] temp during phase-0
    __shared__ int   s_id[192];
    __shared__ float s_wt[192];
    __shared__ float s_qp[3][64];
    __shared__ float s_wq[3][256];
    __shared__ float s_cb[256];
    __shared__ float sw4[64];
    int t = threadIdx.x;
    int w = t >> 6, lane = t & 63;
    int m = lane & 15, quad = lane >> 4;
    int q0 = blockIdx.x * 64;
    int b = q0 >> 14;
    int qin = q0 & (NQ - 1);

    if (t < 192) {
        s_id[t] = knn_idx[q0 * 3 + t];
        s_wt[t] = knn_w[q0 * 3 + t];
        int d = t >> 6, j = t & 63;
        s_qp[d][j] = qpts[(size_t)b * 3 * NQ + d * NQ + qin + j];
    }
    s_wq[0][t] = r1[(size_t)t * 707 + 0];
    s_wq[1][t] = r1[(size_t)t * 707 + 1];
    s_wq[2][t] = r1[(size_t)t * 707 + 2];
    if (t < 64) sw4[t] = r4[t];
    // phase-0a: reduce GMpart rows of this batch (coalesced); max is order-exact
    {
        float mx = 0.f;
        const float* gp = GMpart + (size_t)b * 128 * 256 + t;
        #pragma unroll 8
        for (int r = 0; r < 128; r++) mx = fmaxf(mx, gp[(size_t)r * 256]);
        s_gm[t] = mx;
    }
    __syncthreads();
    // phase-0b: cb[t] = rb1[t] + r1[t,451:707] . gmax  (same fmaf order as before)
    {
        const float* wrow = r1 + (size_t)t * 707 + 451;
        float acc = rb1[t];
        #pragma unroll 8
        for (int c = 0; c < 256; c++) acc = fmaf(wrow[c], s_gm[c], acc);
        s_cb[t] = acc;
    }
    __syncthreads();   // s_cb visible; arena (s_gm) free for sH1

    // ---- interp: build h1 tile [64 q][256 ch] in LDS ----
    {
        int cg = (t & 31) * 8;
        int js = t >> 5;
        float wq0[8], wq1[8], wq2[8], cbv[8];
        #pragma unroll
        for (int u = 0; u < 8; u++) {
            wq0[u] = s_wq[0][cg + u];
            wq1[u] = s_wq[1][cg + u];
            wq2[u] = s_wq[2][cg + u];
            cbv[u] = s_cb[cg + u];
        }
        const _Float16* Gb = G + (size_t)b * NPTS * 256;
        #pragma unroll
        for (int jj = 0; jj < 8; jj++) {
            int j = js + jj * 8;
            int i0 = s_id[j * 3 + 0], i1 = s_id[j * 3 + 1], i2 = s_id[j * 3 + 2];
            float w0 = s_wt[j * 3 + 0], w1 = s_wt[j * 3 + 1], w2 = s_wt[j * 3 + 2];
            float qx = s_qp[0][j], qy = s_qp[1][j], qz = s_qp[2][j];
            h8 g0 = *(const h8*)&Gb[(size_t)i0 * 256 + cg];
            h8 g1 = *(const h8*)&Gb[(size_t)i1 * 256 + cg];
            h8 g2 = *(const h8*)&Gb[(size_t)i2 * 256 + cg];
            h8 hv;
            #pragma unroll
            for (int u = 0; u < 8; u++) {
                float acc = cbv[u];
                acc = fmaf(wq0[u], qx, acc);
                acc = fmaf(wq1[u], qy, acc);
                acc = fmaf(wq2[u], qz, acc);
                acc = fmaf(w0, (float)g0[u], acc);
                acc = fmaf(w1, (float)g1[u], acc);
                acc = fmaf(w2, (float)g2[u], acc);
                hv[u] = (_Float16)fmaxf(acc, 0.f);
            }
            *(h8*)&sH1[j * 264 + cg] = hv;
        }
    }

    // ---- r2: h2(64q x 128ch) = relu(Rw2 @ h1); A-frags straight from sH1 ----
    float h2v[4][2][4];
    {
        v4f acc[4][2];
        #pragma unroll
        for (int i = 0; i < 4; i++)
            #pragma unroll
            for (int j = 0; j < 2; j++)
                acc[i][j] = (v4f){0.f, 0.f, 0.f, 0.f};
        for (int kc = 0; kc < 256; kc += 32) {
            __syncthreads();   // first: sH1 writes; later: sBst reuse
            #pragma unroll
            for (int i = 0; i < 2; i++) {
                int e = t + i * 256;
                int r = e >> 2, p = e & 3;
                *(float4*)&sBst[r * 56 + p * 8] =
                    *(const float4*)&Rw2[(size_t)r * 256 + kc + p * 8];
            }
            __syncthreads();
            h8 af[4], bf[2];
            #pragma unroll
            for (int mt = 0; mt < 4; mt++)
                af[mt] = *(const h8*)&sH1[(mt * 16 + m) * 264 + kc + quad * 8];
            #pragma unroll
            for (int nt = 0; nt < 2; nt++)
                bf[nt] = *(const h8*)&sBst[(w * 32 + nt * 16 + m) * 56 + quad * 8];
            #pragma unroll
            for (int mt = 0; mt < 4; mt++)
                #pragma unroll
                for (int nt = 0; nt < 2; nt++)
                    acc[mt][nt] = __builtin_amdgcn_mfma_f32_16x16x32_f16(
                            af[mt], bf[nt], acc[mt][nt], 0, 0, 0);
        }
        #pragma unroll
        for (int nt = 0; nt < 2; nt++) {
            int ch = w * 32 + nt * 16 + m;
            float bb2 = rb2[ch];
            #pragma unroll
            for (int mt = 0; mt < 4; mt++)
                #pragma unroll
                for (int r = 0; r < 4; r++)
                    h2v[mt][nt][r] = fmaxf(acc[mt][nt][r] + bb2, 0.f);
        }
    }
    __syncthreads();   // all sH1 reads done -> safe to overwrite with sH2
    {
        #pragma unroll
        for (int nt = 0; nt < 2; nt++) {
            int ch = w * 32 + nt * 16 + m;
            #pragma unroll
            for (int mt = 0; mt < 4; mt++)
                #pragma unroll
                for (int r = 0; r < 4; r++) {
                    int ql = mt * 16 + quad * 4 + r;
                    sH2[ql * 136 + ch] = (_Float16)h2v[mt][nt][r];
                }
        }
    }

    // ---- r3: h3(64q x 64ch) = relu(Rw3 @ h2) ----
    float h3v[4][4];
    {
        v4f acc[4];
        #pragma unroll
        for (int i = 0; i < 4; i++) acc[i] = (v4f){0.f, 0.f, 0.f, 0.f};
        for (int kc = 0; kc < 128; kc += 32) {
            __syncthreads();   // first: sH2 writes; later: sW3 reuse
            {
                int r = t >> 2, p = t & 3;   // 64 rows x 4 segs = 256 units
                *(float4*)&sW3[r * 56 + p * 8] =
                    *(const float4*)&Rw3[(size_t)r * 128 + kc + p * 8];
            }
            __syncthreads();
            h8 af[4], bf;
            #pragma unroll
            for (int mt = 0; mt < 4; mt++)
                af[mt] = *(const h8*)&sH2[(mt * 16 + m) * 136 + kc + quad * 8];
            bf = *(const h8*)&sW3[(w * 16 + m) * 56 + quad * 8];
            #pragma unroll
            for (int mt = 0; mt < 4; mt++)
                acc[mt] = __builtin_amdgcn_mfma_f32_16x16x32_f16(
                        af[mt], bf, acc[mt], 0, 0, 0);
        }
        int ch = w * 16 + m;
        float bb3 = rb3[ch];
        #pragma unroll
        for (int mt = 0; mt < 4; mt++)
            #pragma unroll
            for (int r = 0; r < 4; r++)
                h3v[mt][r] = fmaxf(acc[mt][r] + bb3, 0.f);
    }
    __syncthreads();
    {
        int ch = w * 16 + m;
        #pragma unroll
        for (int mt = 0; mt < 4; mt++)
            #pragma unroll
            for (int r = 0; r < 4; r++) {
                int ql = mt * 16 + quad * 4 + r;
                sH3[ch * 72 + ql] = (_Float16)h3v[mt][r];
            }
    }
    __syncthreads();

    // ---- r4: out = r4 . h3 + rb4 ----
    if (t < 64) {
        float acc = rb4[0];
        #pragma unroll 16
        for (int c = 0; c < 64; c++)
            acc = fmaf((float)sH3[c * 72 + t], sw4[c], acc);
        out[q0 + t] = acc;
    }
}

extern "C" void kernel_launch(void* const* d_in, const int* in_sizes, int n_in,
                              void* d_out, int out_size, void* d_ws, size_t ws_size,
                              hipStream_t stream) {
    const float* opts = (const float*)d_in[0];
    const float* qpts = (const float*)d_in[1];
    const float* w1  = (const float*)d_in[2];
    const float* b1  = (const float*)d_in[3];
    const float* w2  = (const float*)d_in[4];
    const float* b2  = (const float*)d_in[5];
    const float* w3  = (const float*)d_in[6];
    const float* b3  = (const float*)d_in[7];
    const float* r1  = (const float*)d_in[8];
    const float* rb1 = (const float*)d_in[9];
    const float* r2  = (const float*)d_in[10];
    const float* rb2 = (const float*)d_in[11];
    const float* r3  = (const float*)d_in[12];
    const float* rb3 = (const float*)d_in[13];
    const float* r4  = (const float*)d_in[14];
    const float* rb4 = (const float*)d_in[15];
    float* out = (float*)d_out;

    unsigned char* p = (unsigned char*)d_ws;
    float* GMpart = (float*)p;      p += (size_t)256 * 256 * 4;       // [blk][ch]
    int*   IDX = (int*)p;           p += (size_t)NB * NQ * 3 * 4;
    float* WT = (float*)p;          p += (size_t)NB * NQ * 3 * 4;
    _Float16* Rw1 = (_Float16*)p;   p += (size_t)256 * FCATC * 2;
    _Float16* Rw2 = (_Float16*)p;   p += (size_t)128 * 256 * 2;
    _Float16* Rw3 = (_Float16*)p;   p += (size_t)64 * 128 * 2;
    _Float16* Ew2 = (_Float16*)p;   p += (size_t)128 * 64 * 2;
    _Float16* Ew3 = (_Float16*)p;   p += (size_t)256 * 128 * 2;
    _Float16* G = (_Float16*)p;     p += (size_t)NB * NPTS * 256 * 2;

    k_pre<<<768, 256, 0, stream>>>(r1, r2, r3, w2, w3, Rw1, Rw2, Rw3, Ew2, Ew3);
    k_feG2<<<256, 256, 0, stream>>>(opts, w1, b1, Ew2, b2, Ew3, b3, Rw1, G, GMpart);
    k_knn<<<512, 512, 0, stream>>>(opts, qpts, IDX, WT);
    k_tail<<<QTOT / 64, 256, 0, stream>>>(qpts, G, GMpart, IDX, WT, r1, rb1,
                                          Rw2, rb2, Rw3, rb3, r4, rb4, out);
}